// Round 4
// baseline (534.141 us; speedup 1.0000x reference)
//
#include <hip/hip_runtime.h>
#include <hip/hip_bf16.h>
#include <stdint.h>

#define BATCH 16384
#define FACE_K 64
#define VISUAL_DIM 2048
#define HIDDEN 512
#define NUM_USERS 1000000
#define NUM_AGES 8
#define NUM_ATTR 40
#define VOCAB (NUM_USERS + 24 + 2 + NUM_AGES + NUM_ATTR)
#define XDIM 384
#define LDS_S 516   // 512 + 4 pad elems; row stride 1032 B -> quad bank offsets {0,8,16,24}

typedef __bf16 bf16x8 __attribute__((ext_vector_type(8)));
typedef float f32x4 __attribute__((ext_vector_type(4)));

__device__ __forceinline__ uint16_t f2bf(float f) {
    union { float f; uint32_t u; } v; v.f = f;
    uint32_t r = v.u + 0x7fffu + ((v.u >> 16) & 1u);
    return (uint16_t)(r >> 16);
}
__device__ __forceinline__ float bf2f(uint16_t h) {
    union { uint32_t u; float f; } v; v.u = ((uint32_t)h) << 16;
    return v.f;
}

// ---------------- fused weight casts: visu_w | w1 | w2 in one launch ----------------
__global__ void cvt_all(const float* __restrict__ visu_w, const float* __restrict__ w1,
                        const float* __restrict__ w2, uint16_t* __restrict__ vwb,
                        uint16_t* __restrict__ w1b, uint16_t* __restrict__ w2b) {
    int i = blockIdx.x * blockDim.x + threadIdx.x;
    const float4* src;
    ushort4* dst;
    if (i < 32768)       { src = (const float4*)visu_w + i;        dst = (ushort4*)vwb + i; }
    else if (i < 81920)  { src = (const float4*)w1 + (i - 32768);  dst = (ushort4*)w1b + (i - 32768); }
    else                 { src = (const float4*)w2 + (i - 81920);  dst = (ushort4*)w2b + (i - 81920); }
    float4 v = *src;
    ushort4 o;
    o.x = f2bf(v.x); o.y = f2bf(v.y); o.z = f2bf(v.z); o.w = f2bf(v.w);
    *dst = o;
}

// ---------------- front kernel: visual GEMM (blocks 0..1023) + embed/FM (1024..5119) ----
#define VIS_BLOCKS 1024
__global__ __launch_bounds__(256) void front_kernel(
        const float* __restrict__ visual, const uint16_t* __restrict__ Wb,
        const float* __restrict__ bias,
        const int* __restrict__ uid, const int* __restrict__ hour,
        const float* __restrict__ scale, const int* __restrict__ gender,
        const int* __restrict__ age, const int* __restrict__ attr,
        const float* __restrict__ user_emb, const float* __restrict__ hour_emb,
        const float* __restrict__ gender_emb, const float* __restrict__ age_emb,
        const float* __restrict__ attr_emb,
        const float* __restrict__ fm_w, const float* __restrict__ fm_b,
        uint16_t* __restrict__ x, float* __restrict__ fm) {
    __shared__ float red[3 * 64 * 17];
    int t = threadIdx.x;
    int wv = t >> 6, lane = t & 63;

    if (blockIdx.x < VIS_BLOCKS) {
        int lc = lane & 15, quad = lane >> 4;
        int m0 = blockIdx.x * 16;
        const float*    ap = visual + (size_t)(m0 + lc) * VISUAL_DIM + wv * 512 + quad * 8;
        const uint16_t* wp = Wb + (size_t)lc * VISUAL_DIM + wv * 512 + quad * 8;

        f32x4 acc[4];
        #pragma unroll
        for (int j = 0; j < 4; ++j) acc[j] = (f32x4){0.f, 0.f, 0.f, 0.f};

        #pragma unroll 4
        for (int k = 0; k < 512; k += 32) {
            float4 a0 = *(const float4*)(ap + k);
            float4 a1 = *(const float4*)(ap + k + 4);
            bf16x8 af;
            af[0] = (__bf16)a0.x; af[1] = (__bf16)a0.y; af[2] = (__bf16)a0.z; af[3] = (__bf16)a0.w;
            af[4] = (__bf16)a1.x; af[5] = (__bf16)a1.y; af[6] = (__bf16)a1.z; af[7] = (__bf16)a1.w;
            #pragma unroll
            for (int j = 0; j < 4; ++j) {
                bf16x8 bf = *(const bf16x8*)(wp + (size_t)(j * 16) * VISUAL_DIM + k);
                acc[j] = __builtin_amdgcn_mfma_f32_16x16x32_bf16(af, bf, acc[j], 0, 0, 0);
            }
        }
        if (wv) {
            int base = (wv - 1) * 1088 + lane * 17;
            #pragma unroll
            for (int j = 0; j < 4; ++j)
                #pragma unroll
                for (int r = 0; r < 4; ++r)
                    red[base + j * 4 + r] = acc[j][r];
        }
        __syncthreads();
        if (wv == 0) {
            int base = lane * 17;
            #pragma unroll
            for (int j = 0; j < 4; ++j) {
                int col = j * 16 + lc;
                float b = bias[col];
                #pragma unroll
                for (int r = 0; r < 4; ++r) {
                    float sum = acc[j][r] + red[base + j * 4 + r]
                              + red[1088 + base + j * 4 + r] + red[2176 + base + j * 4 + r];
                    int row = m0 + quad * 4 + r;
                    x[(size_t)row * XDIM + 320 + col] = f2bf(sum + b);
                }
            }
        }
    } else {
        int row = (blockIdx.x - VIS_BLOCKS) * 4 + wv;
        int u = uid[row], h = hour[row], g = gender[row], a = age[row], at = attr[row];
        float sc = scale[row];
        float eu  = user_emb[(size_t)u * 64 + lane];
        float eh  = hour_emb[h * 64 + lane];
        float eg  = sc * tanhf(gender_emb[g * 64 + lane]);
        float eat = sc * tanhf(attr_emb[at * 64 + lane]);
        float eag = sc * tanhf(age_emb[a * 64 + lane]);
        float s  = eu + eh + eg + eat + eag;
        float sq = eu*eu + eh*eh + eg*eg + eat*eat + eag*eag;
        float so = s * s - sq;
        float l0 = 0.f, l1 = 0.f;
        if (lane < 5) {
            int col = (lane == 0) ? u
                    : (lane == 1) ? (NUM_USERS + h)
                    : (lane == 2) ? (NUM_USERS + 24 + g)
                    : (lane == 3) ? (NUM_USERS + 26 + a)
                    :               (NUM_USERS + 34 + at);
            l0 = fm_w[col];
            l1 = fm_w[VOCAB + col];
        }
        for (int m = 32; m; m >>= 1) {
            so += __shfl_xor(so, m);
            l0 += __shfl_xor(l0, m);
            l1 += __shfl_xor(l1, m);
        }
        if (lane == 0) {
            fm[row * 2 + 0] = l0 + fm_b[0] + 0.5f * so;
            fm[row * 2 + 1] = l1 + fm_b[1] + 0.5f * so;
        }
        size_t xb = (size_t)row * XDIM;
        x[xb +       lane] = f2bf(eu);
        x[xb +  64 + lane] = f2bf(eh);
        x[xb + 128 + lane] = f2bf(eg);
        x[xb + 192 + lane] = f2bf(eat);
        x[xb + 256 + lane] = f2bf(eag);
    }
}

// ---------------- fully-fused DNN: x -> h1(LDS) -> h2 -> dot(w3) -> +fm -> softmax -> out
// block = 256 thr (4 waves): wave = (rg = row-group of 16, cs = col-half of 256)
// grid = BATCH/32 = 512 blocks
__global__ __launch_bounds__(256) void fused_dnn(
        const uint16_t* __restrict__ x, const uint16_t* __restrict__ w1b,
        const float* __restrict__ b1, const uint16_t* __restrict__ w2b,
        const float* __restrict__ b2, const float* __restrict__ w3,
        const float* __restrict__ b3, const float* __restrict__ fm,
        float* __restrict__ out) {
    __shared__ uint16_t h1s[32 * LDS_S];
    __shared__ float dred[2][16][2];
    int t = threadIdx.x;
    int wv = t >> 6, lane = t & 63;
    int rg = wv >> 1, cs = wv & 1;
    int lc = lane & 15, quad = lane >> 4;
    int m0 = blockIdx.x * 32 + rg * 16;

    // ---- stage 1: h1[rg rows][cs*256 .. cs*256+255] ----
    const uint16_t* ap  = x + (size_t)(m0 + lc) * XDIM + quad * 8;
    const uint16_t* wp1 = w1b + (size_t)(cs * 256 + lc) * XDIM + quad * 8;

    f32x4 acc[16];
    #pragma unroll
    for (int j = 0; j < 16; ++j) acc[j] = (f32x4){0.f, 0.f, 0.f, 0.f};

    #pragma unroll 2
    for (int ks = 0; ks < 12; ++ks) {
        bf16x8 af = *(const bf16x8*)(ap + ks * 32);
        #pragma unroll
        for (int j = 0; j < 16; ++j) {
            bf16x8 bf = *(const bf16x8*)(wp1 + (size_t)(j * 16) * XDIM + ks * 32);
            acc[j] = __builtin_amdgcn_mfma_f32_16x16x32_bf16(af, bf, acc[j], 0, 0, 0);
        }
    }
    #pragma unroll
    for (int j = 0; j < 16; ++j) {
        int col = cs * 256 + j * 16 + lc;
        float bb = b1[col];
        #pragma unroll
        for (int r = 0; r < 4; ++r) {
            float v = fmaxf(acc[j][r] + bb, 0.f);
            h1s[(rg * 16 + quad * 4 + r) * LDS_S + col] = f2bf(v);
        }
    }
    __syncthreads();

    // ---- stage 2: h2 cols [cs*256, cs*256+256), K = 512 from LDS ----
    const uint16_t* lp  = h1s + (rg * 16 + lc) * LDS_S + quad * 8;
    const uint16_t* wp2 = w2b + (size_t)(cs * 256 + lc) * HIDDEN + quad * 8;

    f32x4 acc2[16];
    #pragma unroll
    for (int j = 0; j < 16; ++j) acc2[j] = (f32x4){0.f, 0.f, 0.f, 0.f};

    #pragma unroll 2
    for (int ks = 0; ks < 16; ++ks) {
        union { bf16x8 v; ushort4 h[2]; } u;
        u.h[0] = *(const ushort4*)(lp + ks * 32);
        u.h[1] = *(const ushort4*)(lp + ks * 32 + 4);
        bf16x8 af = u.v;
        #pragma unroll
        for (int j = 0; j < 16; ++j) {
            bf16x8 bf = *(const bf16x8*)(wp2 + (size_t)(j * 16) * HIDDEN + ks * 32);
            acc2[j] = __builtin_amdgcn_mfma_f32_16x16x32_bf16(af, bf, acc2[j], 0, 0, 0);
        }
    }

    // ---- relu + dot with w3 ----
    float d0[4] = {0.f, 0.f, 0.f, 0.f}, d1[4] = {0.f, 0.f, 0.f, 0.f};
    #pragma unroll
    for (int j = 0; j < 16; ++j) {
        int col = cs * 256 + j * 16 + lc;
        float bb = b2[col];
        float wa = w3[col], wb2v = w3[HIDDEN + col];
        #pragma unroll
        for (int r = 0; r < 4; ++r) {
            float v = fmaxf(acc2[j][r] + bb, 0.f);
            d0[r] += v * wa;
            d1[r] += v * wb2v;
        }
    }
    #pragma unroll
    for (int m = 1; m <= 8; m <<= 1) {
        #pragma unroll
        for (int r = 0; r < 4; ++r) {
            d0[r] += __shfl_xor(d0[r], m);
            d1[r] += __shfl_xor(d1[r], m);
        }
    }
    if (cs == 1 && lc == 0) {
        #pragma unroll
        for (int r = 0; r < 4; ++r) {
            dred[rg][quad * 4 + r][0] = d0[r];
            dred[rg][quad * 4 + r][1] = d1[r];
        }
    }
    __syncthreads();
    if (cs == 0 && lc == 0) {
        #pragma unroll
        for (int r = 0; r < 4; ++r) {
            int row = m0 + quad * 4 + r;
            float l0 = fm[row * 2 + 0] + d0[r] + dred[rg][quad * 4 + r][0] + b3[0];
            float l1 = fm[row * 2 + 1] + d1[r] + dred[rg][quad * 4 + r][1] + b3[1];
            float mx = fmaxf(l0, l1);
            float e0 = __expf(l0 - mx), e1 = __expf(l1 - mx);
            float inv = 1.f / (e0 + e1);
            out[row * 2 + 0] = e0 * inv;
            out[row * 2 + 1] = e1 * inv;
        }
    }
}

extern "C" void kernel_launch(void* const* d_in, const int* in_sizes, int n_in,
                              void* d_out, int out_size, void* d_ws, size_t ws_size,
                              hipStream_t stream) {
    const int*   user_id   = (const int*)d_in[0];
    const int*   hour      = (const int*)d_in[1];
    const float* visual    = (const float*)d_in[2];
    const float* scale     = (const float*)d_in[3];
    const int*   gender    = (const int*)d_in[4];
    const int*   age       = (const int*)d_in[5];
    const int*   attribute = (const int*)d_in[6];
    const float* user_emb  = (const float*)d_in[7];
    const float* hour_emb  = (const float*)d_in[8];
    const float* gender_emb= (const float*)d_in[9];
    const float* age_emb   = (const float*)d_in[10];
    const float* attr_emb  = (const float*)d_in[11];
    const float* visu_w    = (const float*)d_in[12];
    const float* visu_b    = (const float*)d_in[13];
    const float* fm_w      = (const float*)d_in[14];
    const float* fm_b      = (const float*)d_in[15];
    const float* w1        = (const float*)d_in[16];
    const float* b1        = (const float*)d_in[17];
    const float* w2        = (const float*)d_in[18];
    const float* b2        = (const float*)d_in[19];
    const float* w3        = (const float*)d_in[20];
    const float* b3        = (const float*)d_in[21];
    float* out = (float*)d_out;

    char* ws = (char*)d_ws;
    uint16_t* x   = (uint16_t*)ws;                                  // 16384*384*2 = 12.6 MB
    float*    fm  = (float*)   (ws + 12582912);                     // 16384*2*4
    uint16_t* vwb = (uint16_t*)(ws + 12582912 + 131072);            // 64*2048*2
    uint16_t* w1b = vwb + 64 * 2048;                                // 512*384*2
    uint16_t* w2b = w1b + 512 * 384;                                // 512*512*2

    // all weight casts in one launch
    cvt_all<<<576, 256, 0, stream>>>(visu_w, w1, w2, vwb, w1b, w2b);
    // visual GEMM + embeddings/FM fused (disjoint block ranges)
    front_kernel<<<VIS_BLOCKS + BATCH / 4, 256, 0, stream>>>(
        visual, vwb, visu_b,
        user_id, hour, scale, gender, age, attribute,
        user_emb, hour_emb, gender_emb, age_emb, attr_emb,
        fm_w, fm_b, x, fm);
    // fully-fused DNN (layer1 + layer2 + final + softmax)
    fused_dnn<<<BATCH / 32, 256, 0, stream>>>(x, w1b, b1, w2b, b2, w3, b3, fm, out);
}

// Round 5
// 487.459 us; speedup vs baseline: 1.0958x; 1.0958x over previous
//
#include <hip/hip_runtime.h>
#include <hip/hip_bf16.h>
#include <stdint.h>

#define BATCH 16384
#define FACE_K 64
#define VISUAL_DIM 2048
#define HIDDEN 512
#define NUM_USERS 1000000
#define NUM_AGES 8
#define NUM_ATTR 40
#define VOCAB (NUM_USERS + 24 + 2 + NUM_AGES + NUM_ATTR)
#define XDIM 384
#define XS 388    // x-tile LDS stride (pad +4)
#define HS 516    // h1 LDS stride (pad +4)

typedef __bf16 bf16x8 __attribute__((ext_vector_type(8)));
typedef float f32x4 __attribute__((ext_vector_type(4)));

__device__ __forceinline__ uint16_t f2bf(float f) {
    union { float f; uint32_t u; } v; v.f = f;
    uint32_t r = v.u + 0x7fffu + ((v.u >> 16) & 1u);
    return (uint16_t)(r >> 16);
}

// ---------------- fused weight casts: visu_w | w1 | w2 in one launch ----------------
__global__ void cvt_all(const float* __restrict__ visu_w, const float* __restrict__ w1,
                        const float* __restrict__ w2, uint16_t* __restrict__ vwb,
                        uint16_t* __restrict__ w1b, uint16_t* __restrict__ w2b) {
    int i = blockIdx.x * blockDim.x + threadIdx.x;
    const float4* src;
    ushort4* dst;
    if (i < 32768)       { src = (const float4*)visu_w + i;        dst = (ushort4*)vwb + i; }
    else if (i < 81920)  { src = (const float4*)w1 + (i - 32768);  dst = (ushort4*)w1b + (i - 32768); }
    else                 { src = (const float4*)w2 + (i - 81920);  dst = (ushort4*)w2b + (i - 81920); }
    float4 v = *src;
    ushort4 o;
    o.x = f2bf(v.x); o.y = f2bf(v.y); o.z = f2bf(v.z); o.w = f2bf(v.w);
    *dst = o;
}

// ---------------- mega-kernel: 32 rows per block, end-to-end ----------------
// 4 waves / block, grid = BATCH/32 = 512 blocks (2 blocks/CU)
__global__ __launch_bounds__(256) void mega_kernel(
        const int* __restrict__ uid, const int* __restrict__ hour,
        const float* __restrict__ visual, const float* __restrict__ scale,
        const int* __restrict__ gender, const int* __restrict__ age,
        const int* __restrict__ attr,
        const float* __restrict__ user_emb, const float* __restrict__ hour_emb,
        const float* __restrict__ gender_emb, const float* __restrict__ age_emb,
        const float* __restrict__ attr_emb,
        const uint16_t* __restrict__ vwb, const float* __restrict__ visu_b,
        const float* __restrict__ fm_w, const float* __restrict__ fm_b,
        const uint16_t* __restrict__ w1b, const float* __restrict__ b1,
        const uint16_t* __restrict__ w2b, const float* __restrict__ b2,
        const float* __restrict__ w3, const float* __restrict__ b3,
        float* __restrict__ out) {
    __shared__ uint16_t x_tile[32 * XS];
    __shared__ uint16_t h1s[32 * HS];
    __shared__ float red[2][16 * 64];
    __shared__ float fm_s[32][2];
    __shared__ float dred[4][32][2];

    int t = threadIdx.x;
    int wv = t >> 6, lane = t & 63;
    int lc = lane & 15, quad = lane >> 4;
    int m0 = blockIdx.x * 32;

    // ================= Phase E: embeddings + FM (wave -> 8 rows) =================
    {
        #pragma unroll 2
        for (int r8 = 0; r8 < 8; ++r8) {
            int row_l = wv * 8 + r8;
            int row_g = m0 + row_l;
            int u = uid[row_g], h = hour[row_g], g = gender[row_g];
            int a = age[row_g], at = attr[row_g];
            float sc = scale[row_g];
            float eu  = user_emb[(size_t)u * 64 + lane];
            float eh  = hour_emb[h * 64 + lane];
            float eg  = sc * tanhf(gender_emb[g * 64 + lane]);
            float eat = sc * tanhf(attr_emb[at * 64 + lane]);
            float eag = sc * tanhf(age_emb[a * 64 + lane]);
            float s  = eu + eh + eg + eat + eag;
            float sq = eu*eu + eh*eh + eg*eg + eat*eat + eag*eag;
            float so = s * s - sq;
            float l0 = 0.f, l1 = 0.f;
            if (lane < 5) {
                int col = (lane == 0) ? u
                        : (lane == 1) ? (NUM_USERS + h)
                        : (lane == 2) ? (NUM_USERS + 24 + g)
                        : (lane == 3) ? (NUM_USERS + 26 + a)
                        :               (NUM_USERS + 34 + at);
                l0 = fm_w[col];
                l1 = fm_w[VOCAB + col];
            }
            for (int m = 32; m; m >>= 1) {
                so += __shfl_xor(so, m);
                l0 += __shfl_xor(l0, m);
                l1 += __shfl_xor(l1, m);
            }
            if (lane == 0) {
                fm_s[row_l][0] = l0 + fm_b[0] + 0.5f * so;
                fm_s[row_l][1] = l1 + fm_b[1] + 0.5f * so;
            }
            int xb = row_l * XS;
            x_tile[xb +       lane] = f2bf(eu);
            x_tile[xb +  64 + lane] = f2bf(eh);
            x_tile[xb + 128 + lane] = f2bf(eg);
            x_tile[xb + 192 + lane] = f2bf(eat);
            x_tile[xb + 256 + lane] = f2bf(eag);
        }
    }

    // ================= Phase V: visual projection (wave = rg x kh) =================
    {
        int rg = wv >> 1, kh = wv & 1;
        const float*    va = visual + (size_t)(m0 + rg * 16 + lc) * VISUAL_DIM + kh * 1024 + quad * 8;
        const uint16_t* vb = vwb + (size_t)lc * VISUAL_DIM + kh * 1024 + quad * 8;

        f32x4 acc[4];
        #pragma unroll
        for (int j = 0; j < 4; ++j) acc[j] = (f32x4){0.f, 0.f, 0.f, 0.f};

        #pragma unroll 4
        for (int k = 0; k < 1024; k += 32) {
            float4 a0 = *(const float4*)(va + k);
            float4 a1 = *(const float4*)(va + k + 4);
            bf16x8 af;
            af[0] = (__bf16)a0.x; af[1] = (__bf16)a0.y; af[2] = (__bf16)a0.z; af[3] = (__bf16)a0.w;
            af[4] = (__bf16)a1.x; af[5] = (__bf16)a1.y; af[6] = (__bf16)a1.z; af[7] = (__bf16)a1.w;
            #pragma unroll
            for (int j = 0; j < 4; ++j) {
                bf16x8 bf = *(const bf16x8*)(vb + (size_t)(j * 16) * VISUAL_DIM + k);
                acc[j] = __builtin_amdgcn_mfma_f32_16x16x32_bf16(af, bf, acc[j], 0, 0, 0);
            }
        }
        if (kh == 1) {
            #pragma unroll
            for (int j = 0; j < 4; ++j)
                #pragma unroll
                for (int r = 0; r < 4; ++r)
                    red[rg][(quad * 4 + r) * 64 + j * 16 + lc] = acc[j][r];
        }
        __syncthreads();
        if (kh == 0) {
            #pragma unroll
            for (int j = 0; j < 4; ++j) {
                int col = j * 16 + lc;
                float b = visu_b[col];
                #pragma unroll
                for (int r = 0; r < 4; ++r) {
                    float sum = acc[j][r] + red[rg][(quad * 4 + r) * 64 + col] + b;
                    x_tile[(rg * 16 + quad * 4 + r) * XS + 320 + col] = f2bf(sum);
                }
            }
        }
    }
    __syncthreads();

    // ================= Phase 1: h1 = relu(x @ w1^T + b1), wave = col-quarter ======
    {
        int cs = wv;  // cols cs*128 .. cs*128+127
        const uint16_t* wp1 = w1b + (size_t)(cs * 128 + lc) * XDIM + quad * 8;
        const uint16_t* lp0 = x_tile + lc * XS + quad * 8;
        const uint16_t* lp1 = x_tile + (16 + lc) * XS + quad * 8;

        f32x4 acc[2][8];
        #pragma unroll
        for (int i = 0; i < 2; ++i)
            #pragma unroll
            for (int j = 0; j < 8; ++j) acc[i][j] = (f32x4){0.f, 0.f, 0.f, 0.f};

        #pragma unroll 2
        for (int ks = 0; ks < 12; ++ks) {
            union { bf16x8 v; ushort4 h[2]; } u0, u1;
            u0.h[0] = *(const ushort4*)(lp0 + ks * 32);
            u0.h[1] = *(const ushort4*)(lp0 + ks * 32 + 4);
            u1.h[0] = *(const ushort4*)(lp1 + ks * 32);
            u1.h[1] = *(const ushort4*)(lp1 + ks * 32 + 4);
            #pragma unroll
            for (int j = 0; j < 8; ++j) {
                bf16x8 bf = *(const bf16x8*)(wp1 + (size_t)(j * 16) * XDIM + ks * 32);
                acc[0][j] = __builtin_amdgcn_mfma_f32_16x16x32_bf16(u0.v, bf, acc[0][j], 0, 0, 0);
                acc[1][j] = __builtin_amdgcn_mfma_f32_16x16x32_bf16(u1.v, bf, acc[1][j], 0, 0, 0);
            }
        }
        #pragma unroll
        for (int j = 0; j < 8; ++j) {
            int col = cs * 128 + j * 16 + lc;
            float bb = b1[col];
            #pragma unroll
            for (int i = 0; i < 2; ++i)
                #pragma unroll
                for (int r = 0; r < 4; ++r) {
                    float v = fmaxf(acc[i][j][r] + bb, 0.f);
                    h1s[(i * 16 + quad * 4 + r) * HS + col] = f2bf(v);
                }
        }
    }
    __syncthreads();

    // ================= Phase 2: h2 cols + w3-dot + softmax =================
    {
        int cs = wv;
        const uint16_t* wp2 = w2b + (size_t)(cs * 128 + lc) * HIDDEN + quad * 8;
        const uint16_t* lp0 = h1s + lc * HS + quad * 8;
        const uint16_t* lp1 = h1s + (16 + lc) * HS + quad * 8;

        f32x4 acc[2][8];
        #pragma unroll
        for (int i = 0; i < 2; ++i)
            #pragma unroll
            for (int j = 0; j < 8; ++j) acc[i][j] = (f32x4){0.f, 0.f, 0.f, 0.f};

        #pragma unroll 2
        for (int ks = 0; ks < 16; ++ks) {
            union { bf16x8 v; ushort4 h[2]; } u0, u1;
            u0.h[0] = *(const ushort4*)(lp0 + ks * 32);
            u0.h[1] = *(const ushort4*)(lp0 + ks * 32 + 4);
            u1.h[0] = *(const ushort4*)(lp1 + ks * 32);
            u1.h[1] = *(const ushort4*)(lp1 + ks * 32 + 4);
            #pragma unroll
            for (int j = 0; j < 8; ++j) {
                bf16x8 bf = *(const bf16x8*)(wp2 + (size_t)(j * 16) * HIDDEN + ks * 32);
                acc[0][j] = __builtin_amdgcn_mfma_f32_16x16x32_bf16(u0.v, bf, acc[0][j], 0, 0, 0);
                acc[1][j] = __builtin_amdgcn_mfma_f32_16x16x32_bf16(u1.v, bf, acc[1][j], 0, 0, 0);
            }
        }
        // relu + b2, dot with w3 columns
        float d0[2][4] = {{0,0,0,0},{0,0,0,0}}, d1[2][4] = {{0,0,0,0},{0,0,0,0}};
        #pragma unroll
        for (int j = 0; j < 8; ++j) {
            int col = cs * 128 + j * 16 + lc;
            float bb = b2[col];
            float wa = w3[col], wb = w3[HIDDEN + col];
            #pragma unroll
            for (int i = 0; i < 2; ++i)
                #pragma unroll
                for (int r = 0; r < 4; ++r) {
                    float v = fmaxf(acc[i][j][r] + bb, 0.f);
                    d0[i][r] += v * wa;
                    d1[i][r] += v * wb;
                }
        }
        #pragma unroll
        for (int m = 1; m <= 8; m <<= 1) {
            #pragma unroll
            for (int i = 0; i < 2; ++i)
                #pragma unroll
                for (int r = 0; r < 4; ++r) {
                    d0[i][r] += __shfl_xor(d0[i][r], m);
                    d1[i][r] += __shfl_xor(d1[i][r], m);
                }
        }
        if (lc == 0) {
            #pragma unroll
            for (int i = 0; i < 2; ++i)
                #pragma unroll
                for (int r = 0; r < 4; ++r) {
                    dred[cs][i * 16 + quad * 4 + r][0] = d0[i][r];
                    dred[cs][i * 16 + quad * 4 + r][1] = d1[i][r];
                }
        }
        __syncthreads();
        if (wv == 0 && lc == 0) {
            #pragma unroll
            for (int i = 0; i < 2; ++i)
                #pragma unroll
                for (int r = 0; r < 4; ++r) {
                    int row_l = i * 16 + quad * 4 + r;
                    float l0 = fm_s[row_l][0] + b3[0];
                    float l1 = fm_s[row_l][1] + b3[1];
                    #pragma unroll
                    for (int c = 0; c < 4; ++c) {
                        l0 += dred[c][row_l][0];
                        l1 += dred[c][row_l][1];
                    }
                    float mx = fmaxf(l0, l1);
                    float e0 = __expf(l0 - mx), e1 = __expf(l1 - mx);
                    float inv = 1.f / (e0 + e1);
                    *(float2*)(out + (size_t)(m0 + row_l) * 2) = (float2){e0 * inv, e1 * inv};
                }
        }
    }
}

extern "C" void kernel_launch(void* const* d_in, const int* in_sizes, int n_in,
                              void* d_out, int out_size, void* d_ws, size_t ws_size,
                              hipStream_t stream) {
    const int*   user_id   = (const int*)d_in[0];
    const int*   hour      = (const int*)d_in[1];
    const float* visual    = (const float*)d_in[2];
    const float* scale     = (const float*)d_in[3];
    const int*   gender    = (const int*)d_in[4];
    const int*   age       = (const int*)d_in[5];
    const int*   attribute = (const int*)d_in[6];
    const float* user_emb  = (const float*)d_in[7];
    const float* hour_emb  = (const float*)d_in[8];
    const float* gender_emb= (const float*)d_in[9];
    const float* age_emb   = (const float*)d_in[10];
    const float* attr_emb  = (const float*)d_in[11];
    const float* visu_w    = (const float*)d_in[12];
    const float* visu_b    = (const float*)d_in[13];
    const float* fm_w      = (const float*)d_in[14];
    const float* fm_b      = (const float*)d_in[15];
    const float* w1        = (const float*)d_in[16];
    const float* b1        = (const float*)d_in[17];
    const float* w2        = (const float*)d_in[18];
    const float* b2        = (const float*)d_in[19];
    const float* w3        = (const float*)d_in[20];
    const float* b3        = (const float*)d_in[21];
    float* out = (float*)d_out;

    char* ws = (char*)d_ws;
    uint16_t* vwb = (uint16_t*)ws;            // 64*2048*2
    uint16_t* w1b = vwb + 64 * 2048;          // 512*384*2
    uint16_t* w2b = w1b + 512 * 384;          // 512*512*2

    cvt_all<<<576, 256, 0, stream>>>(visu_w, w1, w2, vwb, w1b, w2b);
    mega_kernel<<<BATCH / 32, 256, 0, stream>>>(
        user_id, hour, visual, scale, gender, age, attribute,
        user_emb, hour_emb, gender_emb, age_emb, attr_emb,
        vwb, visu_b, fm_w, fm_b, w1b, b1, w2b, b2, w3, b3, out);
}